// Round 6
// baseline (745.111 us; speedup 1.0000x reference)
//
#include <hip/hip_runtime.h>
#include <hip/hip_bf16.h>

#define B_ 32
#define C_ 512
#define N_ 4096
#define T_ 72
#define K_ 64
#define KP 80            // clusters padded to 5 MFMA m-tiles
#define EPSF 1e-12f

typedef unsigned short u16;
typedef unsigned int u32;
typedef __attribute__((ext_vector_type(8))) short bf16x8;
typedef __attribute__((ext_vector_type(4))) float f32x4;

__device__ __forceinline__ u16 f2bf(float v) {
    __hip_bfloat16 h = __float2bfloat16(v);   // RNE
    return *reinterpret_cast<u16*>(&h);
}

// ---------------------------------------------------------------------------
// Prep: W padded [80][512] -> bf16 (rows >=72 zero); bias padded (-1e30 pads
// so padded rows vanish in softmax).
// ---------------------------------------------------------------------------
__global__ __launch_bounds__(256) void k_prep(
    const float* __restrict__ conv_w, const float* __restrict__ conv_b,
    u16* __restrict__ Wp, float* __restrict__ bp)
{
    const int idx = blockIdx.x * 256 + threadIdx.x;
    if (idx < KP * C_) {
        const int k = idx >> 9, c = idx & (C_ - 1);
        Wp[idx] = f2bf(k < T_ ? conv_w[k * C_ + c] : 0.f);
    } else if (idx < KP * C_ + KP) {
        const int j = idx - KP * C_;
        bp[j] = (j < T_) ? conv_b[j] : -1e30f;
    }
}

// ---------------------------------------------------------------------------
// Assign v3 (measured ~134 us, FROZEN): n-window 256 so every global load
// instruction is one full 1-KB c-row segment; transpose in registers;
// rotated 16-B c-slots in LDS. 21.5 KB LDS.
// ---------------------------------------------------------------------------
#define ANW 256
__global__ __launch_bounds__(256, 2) void k_assign(
    const float* __restrict__ x, const u16* __restrict__ Wp,
    const float* __restrict__ bp, u16* __restrict__ assignp,
    float* __restrict__ mass)
{
    __shared__ u16   xs[ANW * 32];   // [n 256][c-chunk 32] bf16, 16 KB
    __shared__ float red[4][ANW];    // per-wave sumsq partials
    __shared__ float inv_sh[ANW];

    const int t = threadIdx.x;
    const int b = blockIdx.y;
    const int n0 = blockIdx.x * ANW;
    const int lane = t & 63, w = t >> 6;
    const int q = lane >> 4, nl = lane & 15;

    const float* xb = x + (size_t)b * C_ * N_ + n0 + 4 * lane;

    f32x4 acc[4][5];
    #pragma unroll
    for (int nt = 0; nt < 4; ++nt)
        #pragma unroll
        for (int mt = 0; mt < 5; ++mt) acc[nt][mt] = (f32x4)0.f;
    float ss[4] = {0.f, 0.f, 0.f, 0.f};

    float4 v[8];
    bf16x8 af[5];
    // prologue: chunk 0 (wave w owns c-rows w*8 .. w*8+8 of each chunk)
    #pragma unroll
    for (int i = 0; i < 8; ++i)
        v[i] = *(const float4*)(xb + (size_t)(w * 8 + i) * N_);
    #pragma unroll
    for (int mt = 0; mt < 5; ++mt)
        af[mt] = *(const bf16x8*)(Wp + (size_t)(mt * 16 + nl) * C_ + q * 8);

#define VJ(i) (j == 0 ? v[i].x : j == 1 ? v[i].y : j == 2 ? v[i].z : v[i].w)

    #pragma unroll 1
    for (int ch = 0; ch < 16; ++ch) {
        // ---- consume registers: sumsq + c-contiguous LDS write ----
        #pragma unroll
        for (int j = 0; j < 4; ++j) {
            const float f0 = VJ(0), f1 = VJ(1), f2 = VJ(2), f3 = VJ(3);
            const float f4 = VJ(4), f5 = VJ(5), f6 = VJ(6), f7 = VJ(7);
            ss[j] = fmaf(f0, f0, ss[j]); ss[j] = fmaf(f1, f1, ss[j]);
            ss[j] = fmaf(f2, f2, ss[j]); ss[j] = fmaf(f3, f3, ss[j]);
            ss[j] = fmaf(f4, f4, ss[j]); ss[j] = fmaf(f5, f5, ss[j]);
            ss[j] = fmaf(f6, f6, ss[j]); ss[j] = fmaf(f7, f7, ss[j]);
            uint4 pk;
            pk.x = (u32)f2bf(f0) | ((u32)f2bf(f1) << 16);
            pk.y = (u32)f2bf(f2) | ((u32)f2bf(f3) << 16);
            pk.z = (u32)f2bf(f4) | ((u32)f2bf(f5) << 16);
            pk.w = (u32)f2bf(f6) | ((u32)f2bf(f7) << 16);
            const int n = 4 * lane + j;
            const int slot = (w + ((lane >> 1) & 3)) & 3;   // rotated c-slot
            *(uint4*)&xs[n * 32 + slot * 8] = pk;
        }
        __syncthreads();
        // ---- prefetch next chunk's x rows (in flight across MFMA) ----
        if (ch < 15) {
            #pragma unroll
            for (int i = 0; i < 8; ++i)
                v[i] = *(const float4*)(xb + (size_t)((ch + 1) * 32 + w * 8 + i) * N_);
        }
        __builtin_amdgcn_sched_barrier(0);
        // ---- MFMA: 4 n-tiles x 5 m-tiles, K=32 (this chunk) ----
        #pragma unroll
        for (int nt = 0; nt < 4; ++nt) {
            const int n = (4 * w + nt) * 16 + nl;
            const int slot = (q + ((n >> 3) & 3)) & 3;
            const bf16x8 bfr = *(const bf16x8*)&xs[n * 32 + slot * 8];
            #pragma unroll
            for (int mt = 0; mt < 5; ++mt)
                acc[nt][mt] = __builtin_amdgcn_mfma_f32_16x16x32_bf16(af[mt], bfr, acc[nt][mt], 0, 0, 0);
        }
        // ---- prefetch next chunk's W fragments (L2-hot) ----
        if (ch < 15) {
            #pragma unroll
            for (int mt = 0; mt < 5; ++mt)
                af[mt] = *(const bf16x8*)(Wp + (size_t)(mt * 16 + nl) * C_ + (ch + 1) * 32 + q * 8);
        }
        __syncthreads();
    }
#undef VJ

    // ---- cross-wave sumsq reduction -> inv norms ----
    *(float4*)&red[w][4 * lane] = make_float4(ss[0], ss[1], ss[2], ss[3]);
    __syncthreads();
    {
        const float s = red[0][t] + red[1][t] + red[2][t] + red[3][t];
        inv_sh[t] = 1.0f / fmaxf(sqrtf(s), EPSF);
    }
    __syncthreads();

    float bpv[5][4];
    #pragma unroll
    for (int mt = 0; mt < 5; ++mt)
        #pragma unroll
        for (int r = 0; r < 4; ++r) bpv[mt][r] = bp[mt * 16 + q * 4 + r];

    // ---- epilogue per n-tile: softmax in C-layout regs (proven math) ----
    #pragma unroll
    for (int nt = 0; nt < 4; ++nt) {
        const int n_loc = (4 * w + nt) * 16 + nl;
        const float invn = inv_sh[n_loc];
        const int nglob = n0 + n_loc;

        float lg[5][4];
        #pragma unroll
        for (int mt = 0; mt < 5; ++mt)
            #pragma unroll
            for (int r = 0; r < 4; ++r)
                lg[mt][r] = acc[nt][mt][r] * invn + bpv[mt][r];

        float mx = -1e30f;
        #pragma unroll
        for (int mt = 0; mt < 5; ++mt)
            #pragma unroll
            for (int r = 0; r < 4; ++r) mx = fmaxf(mx, lg[mt][r]);
        mx = fmaxf(mx, __shfl_xor(mx, 16, 64));
        mx = fmaxf(mx, __shfl_xor(mx, 32, 64));

        float s = 0.f;
        #pragma unroll
        for (int mt = 0; mt < 5; ++mt)
            #pragma unroll
            for (int r = 0; r < 4; ++r) {
                lg[mt][r] = __expf(lg[mt][r] - mx);
                s += lg[mt][r];
            }
        s += __shfl_xor(s, 16, 64);
        s += __shfl_xor(s, 32, 64);
        const float rs = 1.0f / s;

        #pragma unroll
        for (int mt = 0; mt < 4; ++mt)      // real clusters only
            #pragma unroll
            for (int r = 0; r < 4; ++r) {
                const float a = lg[mt][r] * rs;
                float msum = a;
                msum += __shfl_xor(msum, 1, 64);
                msum += __shfl_xor(msum, 2, 64);
                msum += __shfl_xor(msum, 4, 64);
                msum += __shfl_xor(msum, 8, 64);
                const int k = mt * 16 + q * 4 + r;
                if (nl == 0) atomicAdd(&mass[b * K_ + k], msum);
                assignp[((size_t)b * K_ + k) * N_ + nglob] = f2bf(a * invn);
            }
    }
}

// ---------------------------------------------------------------------------
// Agg v5 (FROZEN from round 5): all-LDS MFMA, prefetch-1, 34.8 KB LDS.
// ---------------------------------------------------------------------------
#define AGW 1024
#define AGS 128
#define AGP 136
__global__ __launch_bounds__(256) void k_agg(
    const float* __restrict__ x, const u16* __restrict__ assignp,
    float* __restrict__ out)
{
    __shared__ u16 At[K_][AGP];   // 64 k x 128 n bf16, 17,408 B
    __shared__ u16 Bt[K_][AGP];   // 64 c x 128 n bf16, 17,408 B

    const int t = threadIdx.x, b = blockIdx.z;
    const int nc0 = blockIdx.y * AGW;
    const int c0 = blockIdx.x * 64;
    const int lane = t & 63, w = t >> 6;
    const int q = lane >> 4, nl = lane & 15;

    const int as = lane & 15, ar = lane >> 4;   // A: 16-B n-slot, row-in-4
    const int bs = lane & 31, br = lane >> 5;   // B: float4 n-slot, row-in-2

    f32x4 acc[4];
    #pragma unroll
    for (int mt = 0; mt < 4; ++mt) acc[mt] = (f32x4)0.f;

    const u16*   ab = assignp + (size_t)b * K_ * N_;
    const float* xb = x + ((size_t)b * C_ + c0) * N_;

    uint4  ra[4];
    float4 rb[8];
    #pragma unroll
    for (int i = 0; i < 4; ++i)
        ra[i] = *(const uint4*)(ab + (size_t)(16 * w + 4 * i + ar) * N_ + nc0 + as * 8);
    #pragma unroll
    for (int i = 0; i < 8; ++i)
        rb[i] = *(const float4*)(xb + (size_t)(16 * w + 2 * i + br) * N_ + nc0 + bs * 4);

    #pragma unroll 1
    for (int ph = 0; ph < AGW / AGS; ++ph) {
        #pragma unroll
        for (int i = 0; i < 4; ++i)
            *(uint4*)&At[16 * w + 4 * i + ar][as * 8] = ra[i];
        #pragma unroll
        for (int i = 0; i < 8; ++i) {
            const float4 vv = rb[i];
            uint2 pk;
            pk.x = (u32)f2bf(vv.x) | ((u32)f2bf(vv.y) << 16);
            pk.y = (u32)f2bf(vv.z) | ((u32)f2bf(vv.w) << 16);
            *(uint2*)&Bt[16 * w + 2 * i + br][bs * 4] = pk;
        }
        __syncthreads();
        if (ph < AGW / AGS - 1) {
            const int n1 = nc0 + (ph + 1) * AGS;
            #pragma unroll
            for (int i = 0; i < 4; ++i)
                ra[i] = *(const uint4*)(ab + (size_t)(16 * w + 4 * i + ar) * N_ + n1 + as * 8);
            #pragma unroll
            for (int i = 0; i < 8; ++i)
                rb[i] = *(const float4*)(xb + (size_t)(16 * w + 2 * i + br) * N_ + n1 + bs * 4);
        }
        __builtin_amdgcn_sched_barrier(0);
        #pragma unroll
        for (int ks = 0; ks < 4; ++ks) {
            const bf16x8 bfr = *(const bf16x8*)&Bt[16 * w + nl][ks * 32 + q * 8];
            #pragma unroll
            for (int mt = 0; mt < 4; ++mt) {
                const bf16x8 afv = *(const bf16x8*)&At[mt * 16 + nl][ks * 32 + q * 8];
                acc[mt] = __builtin_amdgcn_mfma_f32_16x16x32_bf16(afv, bfr, acc[mt], 0, 0, 0);
            }
        }
        __syncthreads();
    }

    float* ob = out + (size_t)b * K_ * C_;
    const int c = c0 + 16 * w + nl;
    #pragma unroll
    for (int mt = 0; mt < 4; ++mt)
        #pragma unroll
        for (int r = 0; r < 4; ++r)
            atomicAdd(&ob[(size_t)(mt * 16 + q * 4 + r) * C_ + c], acc[mt][r]);
}

// ---------------------------------------------------------------------------
// PROBE (this round only): exact k_agg body repeated 3x, output -> ws scratch.
// Purpose: dur(probe) = 3 * dur(k_agg); lands in rocprof top-5 with full
// counters if k_agg >= ~54 us. Total dur_us = 517 + 3X pins X regardless.
// Correctness-neutral: writes only to scratch.
// ---------------------------------------------------------------------------
#define AGREP 3
__global__ __launch_bounds__(256) void k_agg_probe(
    const float* __restrict__ x, const u16* __restrict__ assignp,
    float* __restrict__ out)
{
    __shared__ u16 At[K_][AGP];
    __shared__ u16 Bt[K_][AGP];

    const int t = threadIdx.x, b = blockIdx.z;
    const int nc0 = blockIdx.y * AGW;
    const int c0 = blockIdx.x * 64;
    const int lane = t & 63, w = t >> 6;
    const int q = lane >> 4, nl = lane & 15;

    const int as = lane & 15, ar = lane >> 4;
    const int bs = lane & 31, br = lane >> 5;

    f32x4 acc[4];
    #pragma unroll
    for (int mt = 0; mt < 4; ++mt) acc[mt] = (f32x4)0.f;

    const u16*   ab = assignp + (size_t)b * K_ * N_;
    const float* xb = x + ((size_t)b * C_ + c0) * N_;

    #pragma unroll 1
    for (int rep = 0; rep < AGREP; ++rep) {
        uint4  ra[4];
        float4 rb[8];
        #pragma unroll
        for (int i = 0; i < 4; ++i)
            ra[i] = *(const uint4*)(ab + (size_t)(16 * w + 4 * i + ar) * N_ + nc0 + as * 8);
        #pragma unroll
        for (int i = 0; i < 8; ++i)
            rb[i] = *(const float4*)(xb + (size_t)(16 * w + 2 * i + br) * N_ + nc0 + bs * 4);

        #pragma unroll 1
        for (int ph = 0; ph < AGW / AGS; ++ph) {
            #pragma unroll
            for (int i = 0; i < 4; ++i)
                *(uint4*)&At[16 * w + 4 * i + ar][as * 8] = ra[i];
            #pragma unroll
            for (int i = 0; i < 8; ++i) {
                const float4 vv = rb[i];
                uint2 pk;
                pk.x = (u32)f2bf(vv.x) | ((u32)f2bf(vv.y) << 16);
                pk.y = (u32)f2bf(vv.z) | ((u32)f2bf(vv.w) << 16);
                *(uint2*)&Bt[16 * w + 2 * i + br][bs * 4] = pk;
            }
            __syncthreads();
            if (ph < AGW / AGS - 1) {
                const int n1 = nc0 + (ph + 1) * AGS;
                #pragma unroll
                for (int i = 0; i < 4; ++i)
                    ra[i] = *(const uint4*)(ab + (size_t)(16 * w + 4 * i + ar) * N_ + n1 + as * 8);
                #pragma unroll
                for (int i = 0; i < 8; ++i)
                    rb[i] = *(const float4*)(xb + (size_t)(16 * w + 2 * i + br) * N_ + n1 + bs * 4);
            }
            __builtin_amdgcn_sched_barrier(0);
            #pragma unroll
            for (int ks = 0; ks < 4; ++ks) {
                const bf16x8 bfr = *(const bf16x8*)&Bt[16 * w + nl][ks * 32 + q * 8];
                #pragma unroll
                for (int mt = 0; mt < 4; ++mt) {
                    const bf16x8 afv = *(const bf16x8*)&At[mt * 16 + nl][ks * 32 + q * 8];
                    acc[mt] = __builtin_amdgcn_mfma_f32_16x16x32_bf16(afv, bfr, acc[mt], 0, 0, 0);
                }
            }
            __syncthreads();
        }
    }

    float* ob = out + (size_t)b * K_ * C_;
    const int c = c0 + 16 * w + nl;
    #pragma unroll
    for (int mt = 0; mt < 4; ++mt)
        #pragma unroll
        for (int r = 0; r < 4; ++r)
            atomicAdd(&ob[(size_t)(mt * 16 + q * 4 + r) * C_ + c], acc[mt][r]);
}

// ---------------------------------------------------------------------------
// Row norms + global norm (fp32 exact), unchanged.
// ---------------------------------------------------------------------------
__device__ __forceinline__ float block_reduce_sum_256(float v) {
    #pragma unroll
    for (int o = 32; o > 0; o >>= 1) v += __shfl_down(v, o, 64);
    __shared__ float wsh[4];
    const int lane = threadIdx.x & 63, wid = threadIdx.x >> 6;
    if (lane == 0) wsh[wid] = v;
    __syncthreads();
    float r = 0.f;
    if (threadIdx.x == 0) r = wsh[0] + wsh[1] + wsh[2] + wsh[3];
    return r;
}

__global__ __launch_bounds__(256) void k_rnorm(
    const float* __restrict__ agg, const float* __restrict__ centroids,
    const float* __restrict__ mass, float* __restrict__ rnorm,
    float* __restrict__ gsum)
{
    const int k = blockIdx.x, b = blockIdx.y;
    const float mk = mass[b * K_ + k];
    const float* p  = agg + ((size_t)b * K_ + k) * C_;
    const float* cb = centroids + k * C_;
    float s = 0.f;
    #pragma unroll 2
    for (int i = threadIdx.x; i < C_; i += 256) {
        const float v = fmaf(-cb[i], mk, p[i]);
        s = fmaf(v, v, s);
    }
    const float ss = block_reduce_sum_256(s);
    if (threadIdx.x == 0) {
        const float rn = fmaxf(sqrtf(ss), EPSF);
        rnorm[b * K_ + k] = rn;
        atomicAdd(gsum + b, ss / (rn * rn));
    }
}

__global__ __launch_bounds__(256) void k_final(
    float* __restrict__ out, const float* __restrict__ centroids,
    const float* __restrict__ mass, const float* __restrict__ rnorm,
    const float* __restrict__ gsum)
{
    const size_t i4 = ((size_t)blockIdx.x * 256 + threadIdx.x) * 4;
    const int b = (int)(i4 >> 15);
    const int k = (int)((i4 >> 9) & 63);
    const int c = (int)(i4 & 511);
    const float gn = fmaxf(sqrtf(gsum[b]), EPSF);
    const float sc = 1.0f / (rnorm[b * K_ + k] * gn);
    const float mk = mass[b * K_ + k];
    float4 v  = *(const float4*)(out + i4);
    const float4 cv = *(const float4*)(centroids + k * C_ + c);
    v.x = fmaf(-cv.x, mk, v.x) * sc;
    v.y = fmaf(-cv.y, mk, v.y) * sc;
    v.z = fmaf(-cv.z, mk, v.z) * sc;
    v.w = fmaf(-cv.w, mk, v.w) * sc;
    *(float4*)(out + i4) = v;
}

// ---------------------------------------------------------------------------
extern "C" void kernel_launch(void* const* d_in, const int* in_sizes, int n_in,
                              void* d_out, int out_size, void* d_ws, size_t ws_size,
                              hipStream_t stream) {
    const float* x         = (const float*)d_in[0];
    const float* centroids = (const float*)d_in[1];
    const float* conv_w    = (const float*)d_in[2];
    const float* conv_b    = (const float*)d_in[3];
    // d_in[4..8] (ghost_weights, w1, b1, w2, b2): positive per-row scalars
    // cancel inside the intra-cluster L2 norm; ghost rows dropped -> unused.

    float* out = (float*)d_out;
    char*  ws  = (char*)d_ws;

    u16*   assignp = (u16*)ws;                               // 16,777,216 B
    u16*   Wp      = (u16*)(ws + 16777216);                  // 81,920 B
    float* bpad    = (float*)(ws + 16777216 + 81920);        // 320 B
    float* mass    = (float*)(ws + 16777216 + 81920 + 320);  // 8 KB
    float* rnorm   = mass + B_ * K_;
    float* gsum    = rnorm + B_ * K_;
    float* scratch = (float*)(ws + (size_t)128 * 1024 * 1024);  // probe sink

    hipMemsetAsync(mass, 0, B_ * K_ * sizeof(float), stream);
    hipMemsetAsync(gsum, 0, B_ * sizeof(float), stream);
    hipMemsetAsync(out, 0, (size_t)out_size * sizeof(float), stream);

    k_prep<<<dim3((KP * C_ + KP + 255) / 256), 256, 0, stream>>>(conv_w, conv_b, Wp, bpad);
    k_assign<<<dim3(N_ / ANW, B_), 256, 0, stream>>>(x, Wp, bpad, assignp, mass);
    k_agg<<<dim3(C_ / 64, N_ / AGW, B_), 256, 0, stream>>>(x, assignp, out);
    k_rnorm<<<dim3(K_, B_), 256, 0, stream>>>(out, centroids, mass, rnorm, gsum);
    k_final<<<(out_size / 4 + 255) / 256, 256, 0, stream>>>(out, centroids, mass, rnorm, gsum);
    // measurement probe (this round only): 3x k_agg into scratch
    k_agg_probe<<<dim3(C_ / 64, N_ / AGW, B_), 256, 0, stream>>>(x, assignp, scratch);
}

// Round 7
// 560.510 us; speedup vs baseline: 1.3293x; 1.3293x over previous
//
#include <hip/hip_runtime.h>
#include <hip/hip_bf16.h>

#define B_ 32
#define C_ 512
#define N_ 4096
#define T_ 72
#define K_ 64
#define KP 80            // clusters padded to 5 MFMA m-tiles
#define EPSF 1e-12f

typedef unsigned short u16;
typedef unsigned int u32;
typedef __attribute__((ext_vector_type(8))) short bf16x8;
typedef __attribute__((ext_vector_type(4))) float f32x4;

__device__ __forceinline__ u16 f2bf(float v) {
    __hip_bfloat16 h = __float2bfloat16(v);   // RNE
    return *reinterpret_cast<u16*>(&h);
}

// ---------------------------------------------------------------------------
// Prep + zero-init (replaces 3 hipMemsetAsync dispatches):
//  - zero out[4 MB] (float4) + mass[2048]
//  - W padded [80][512] -> bf16 ; bias padded (-1e30)
// grid 1032 x 256 covers 264,192 zero-slots and the 41,040 prep slots.
// ---------------------------------------------------------------------------
__global__ __launch_bounds__(256) void k_prep(
    const float* __restrict__ conv_w, const float* __restrict__ conv_b,
    u16* __restrict__ Wp, float* __restrict__ bp,
    float* __restrict__ out, float* __restrict__ mass)
{
    const int idx = blockIdx.x * 256 + threadIdx.x;
    if (idx < (B_ * K_ * C_) / 4)
        ((float4*)out)[idx] = make_float4(0.f, 0.f, 0.f, 0.f);
    else if (idx < (B_ * K_ * C_) / 4 + B_ * K_)
        mass[idx - (B_ * K_ * C_) / 4] = 0.f;

    if (idx < KP * C_) {
        const int k = idx >> 9, c = idx & (C_ - 1);
        Wp[idx] = f2bf(k < T_ ? conv_w[k * C_ + c] : 0.f);
    } else if (idx < KP * C_ + KP) {
        const int j = idx - KP * C_;
        bp[j] = (j < T_) ? conv_b[j] : -1e30f;
    }
}

// ---------------------------------------------------------------------------
// Assign v4: v3 (~134 us) + stores raw-x bf16 (xbf, n-contiguous) for k_agg,
// reusing the f2bf conversions it already performs. Everything else frozen.
// ---------------------------------------------------------------------------
#define ANW 256
__global__ __launch_bounds__(256, 2) void k_assign(
    const float* __restrict__ x, const u16* __restrict__ Wp,
    const float* __restrict__ bp, u16* __restrict__ assignp,
    u16* __restrict__ xbf, float* __restrict__ mass)
{
    __shared__ u16   xs[ANW * 32];   // [n 256][c-chunk 32] bf16, 16 KB
    __shared__ float red[4][ANW];    // per-wave sumsq partials
    __shared__ float inv_sh[ANW];

    const int t = threadIdx.x;
    const int b = blockIdx.y;
    const int n0 = blockIdx.x * ANW;
    const int lane = t & 63, w = t >> 6;
    const int q = lane >> 4, nl = lane & 15;

    const float* xb = x + (size_t)b * C_ * N_ + n0 + 4 * lane;

    f32x4 acc[4][5];
    #pragma unroll
    for (int nt = 0; nt < 4; ++nt)
        #pragma unroll
        for (int mt = 0; mt < 5; ++mt) acc[nt][mt] = (f32x4)0.f;
    float ss[4] = {0.f, 0.f, 0.f, 0.f};

    float4 v[8];
    bf16x8 af[5];
    // prologue: chunk 0 (wave w owns c-rows w*8 .. w*8+8 of each chunk)
    #pragma unroll
    for (int i = 0; i < 8; ++i)
        v[i] = *(const float4*)(xb + (size_t)(w * 8 + i) * N_);
    #pragma unroll
    for (int mt = 0; mt < 5; ++mt)
        af[mt] = *(const bf16x8*)(Wp + (size_t)(mt * 16 + nl) * C_ + q * 8);

#define VJ(i) (j == 0 ? v[i].x : j == 1 ? v[i].y : j == 2 ? v[i].z : v[i].w)

    #pragma unroll 1
    for (int ch = 0; ch < 16; ++ch) {
        // ---- xbf store: raw-x bf16, n-contiguous (reuses the same cvts) ----
        #pragma unroll
        for (int i = 0; i < 8; ++i) {
            uint2 px;
            px.x = (u32)f2bf(v[i].x) | ((u32)f2bf(v[i].y) << 16);
            px.y = (u32)f2bf(v[i].z) | ((u32)f2bf(v[i].w) << 16);
            *(uint2*)(xbf + ((size_t)b * C_ + ch * 32 + w * 8 + i) * N_ + n0 + 4 * lane) = px;
        }
        // ---- consume registers: sumsq + c-contiguous LDS write ----
        #pragma unroll
        for (int j = 0; j < 4; ++j) {
            const float f0 = VJ(0), f1 = VJ(1), f2 = VJ(2), f3 = VJ(3);
            const float f4 = VJ(4), f5 = VJ(5), f6 = VJ(6), f7 = VJ(7);
            ss[j] = fmaf(f0, f0, ss[j]); ss[j] = fmaf(f1, f1, ss[j]);
            ss[j] = fmaf(f2, f2, ss[j]); ss[j] = fmaf(f3, f3, ss[j]);
            ss[j] = fmaf(f4, f4, ss[j]); ss[j] = fmaf(f5, f5, ss[j]);
            ss[j] = fmaf(f6, f6, ss[j]); ss[j] = fmaf(f7, f7, ss[j]);
            uint4 pk;
            pk.x = (u32)f2bf(f0) | ((u32)f2bf(f1) << 16);
            pk.y = (u32)f2bf(f2) | ((u32)f2bf(f3) << 16);
            pk.z = (u32)f2bf(f4) | ((u32)f2bf(f5) << 16);
            pk.w = (u32)f2bf(f6) | ((u32)f2bf(f7) << 16);
            const int n = 4 * lane + j;
            const int slot = (w + ((lane >> 1) & 3)) & 3;   // rotated c-slot
            *(uint4*)&xs[n * 32 + slot * 8] = pk;
        }
        __syncthreads();
        // ---- prefetch next chunk's x rows (in flight across MFMA) ----
        if (ch < 15) {
            #pragma unroll
            for (int i = 0; i < 8; ++i)
                v[i] = *(const float4*)(xb + (size_t)((ch + 1) * 32 + w * 8 + i) * N_);
        }
        __builtin_amdgcn_sched_barrier(0);
        // ---- MFMA: 4 n-tiles x 5 m-tiles, K=32 (this chunk) ----
        #pragma unroll
        for (int nt = 0; nt < 4; ++nt) {
            const int n = (4 * w + nt) * 16 + nl;
            const int slot = (q + ((n >> 3) & 3)) & 3;
            const bf16x8 bfr = *(const bf16x8*)&xs[n * 32 + slot * 8];
            #pragma unroll
            for (int mt = 0; mt < 5; ++mt)
                acc[nt][mt] = __builtin_amdgcn_mfma_f32_16x16x32_bf16(af[mt], bfr, acc[nt][mt], 0, 0, 0);
        }
        // ---- prefetch next chunk's W fragments (L2-hot) ----
        if (ch < 15) {
            #pragma unroll
            for (int mt = 0; mt < 5; ++mt)
                af[mt] = *(const bf16x8*)(Wp + (size_t)(mt * 16 + nl) * C_ + (ch + 1) * 32 + q * 8);
        }
        __syncthreads();
    }
#undef VJ

    // ---- cross-wave sumsq reduction -> inv norms ----
    *(float4*)&red[w][4 * lane] = make_float4(ss[0], ss[1], ss[2], ss[3]);
    __syncthreads();
    {
        const float s = red[0][t] + red[1][t] + red[2][t] + red[3][t];
        inv_sh[t] = 1.0f / fmaxf(sqrtf(s), EPSF);
    }
    __syncthreads();

    float bpv[5][4];
    #pragma unroll
    for (int mt = 0; mt < 5; ++mt)
        #pragma unroll
        for (int r = 0; r < 4; ++r) bpv[mt][r] = bp[mt * 16 + q * 4 + r];

    // ---- epilogue per n-tile: softmax in C-layout regs (proven math) ----
    #pragma unroll
    for (int nt = 0; nt < 4; ++nt) {
        const int n_loc = (4 * w + nt) * 16 + nl;
        const float invn = inv_sh[n_loc];
        const int nglob = n0 + n_loc;

        float lg[5][4];
        #pragma unroll
        for (int mt = 0; mt < 5; ++mt)
            #pragma unroll
            for (int r = 0; r < 4; ++r)
                lg[mt][r] = acc[nt][mt][r] * invn + bpv[mt][r];

        float mx = -1e30f;
        #pragma unroll
        for (int mt = 0; mt < 5; ++mt)
            #pragma unroll
            for (int r = 0; r < 4; ++r) mx = fmaxf(mx, lg[mt][r]);
        mx = fmaxf(mx, __shfl_xor(mx, 16, 64));
        mx = fmaxf(mx, __shfl_xor(mx, 32, 64));

        float s = 0.f;
        #pragma unroll
        for (int mt = 0; mt < 5; ++mt)
            #pragma unroll
            for (int r = 0; r < 4; ++r) {
                lg[mt][r] = __expf(lg[mt][r] - mx);
                s += lg[mt][r];
            }
        s += __shfl_xor(s, 16, 64);
        s += __shfl_xor(s, 32, 64);
        const float rs = 1.0f / s;

        #pragma unroll
        for (int mt = 0; mt < 4; ++mt)      // real clusters only
            #pragma unroll
            for (int r = 0; r < 4; ++r) {
                const float a = lg[mt][r] * rs;
                float msum = a;
                msum += __shfl_xor(msum, 1, 64);
                msum += __shfl_xor(msum, 2, 64);
                msum += __shfl_xor(msum, 4, 64);
                msum += __shfl_xor(msum, 8, 64);
                const int k = mt * 16 + q * 4 + r;
                if (nl == 0) atomicAdd(&mass[b * K_ + k], msum);
                assignp[((size_t)b * K_ + k) * N_ + nglob] = f2bf(a * invn);
            }
    }
}

// ---------------------------------------------------------------------------
// Agg v6: identical structure to v5 (all-LDS MFMA, prefetch-1) but the B
// operand comes from xbf (bf16) -> FETCH halves (206 -> ~90 MB) and staging
// has zero cvt math (uint4 copies for both A and B).
// ---------------------------------------------------------------------------
#define AGW 1024
#define AGS 128
#define AGP 136
__global__ __launch_bounds__(256) void k_agg(
    const u16* __restrict__ xbf, const u16* __restrict__ assignp,
    float* __restrict__ out)
{
    __shared__ u16 At[K_][AGP];   // 64 k x 128 n bf16, 17,408 B
    __shared__ u16 Bt[K_][AGP];   // 64 c x 128 n bf16, 17,408 B

    const int t = threadIdx.x, b = blockIdx.z;
    const int nc0 = blockIdx.y * AGW;
    const int c0 = blockIdx.x * 64;
    const int lane = t & 63, w = t >> 6;
    const int q = lane >> 4, nl = lane & 15;

    const int as = lane & 15, ar = lane >> 4;   // 16-B n-slot, row-in-4

    f32x4 acc[4];
    #pragma unroll
    for (int mt = 0; mt < 4; ++mt) acc[mt] = (f32x4)0.f;

    const u16* ab  = assignp + (size_t)b * K_ * N_;
    const u16* xbb = xbf + ((size_t)b * C_ + c0) * N_;

    uint4 ra[4], rb[4];
    #pragma unroll
    for (int i = 0; i < 4; ++i) {
        ra[i] = *(const uint4*)(ab  + (size_t)(16 * w + 4 * i + ar) * N_ + nc0 + as * 8);
        rb[i] = *(const uint4*)(xbb + (size_t)(16 * w + 4 * i + ar) * N_ + nc0 + as * 8);
    }

    #pragma unroll 1
    for (int ph = 0; ph < AGW / AGS; ++ph) {
        #pragma unroll
        for (int i = 0; i < 4; ++i) {
            *(uint4*)&At[16 * w + 4 * i + ar][as * 8] = ra[i];
            *(uint4*)&Bt[16 * w + 4 * i + ar][as * 8] = rb[i];
        }
        __syncthreads();
        if (ph < AGW / AGS - 1) {
            const int n1 = nc0 + (ph + 1) * AGS;
            #pragma unroll
            for (int i = 0; i < 4; ++i) {
                ra[i] = *(const uint4*)(ab  + (size_t)(16 * w + 4 * i + ar) * N_ + n1 + as * 8);
                rb[i] = *(const uint4*)(xbb + (size_t)(16 * w + 4 * i + ar) * N_ + n1 + as * 8);
            }
        }
        __builtin_amdgcn_sched_barrier(0);
        #pragma unroll
        for (int ks = 0; ks < 4; ++ks) {
            const bf16x8 bfr = *(const bf16x8*)&Bt[16 * w + nl][ks * 32 + q * 8];
            #pragma unroll
            for (int mt = 0; mt < 4; ++mt) {
                const bf16x8 afv = *(const bf16x8*)&At[mt * 16 + nl][ks * 32 + q * 8];
                acc[mt] = __builtin_amdgcn_mfma_f32_16x16x32_bf16(afv, bfr, acc[mt], 0, 0, 0);
            }
        }
        __syncthreads();
    }

    float* ob = out + (size_t)b * K_ * C_;
    const int c = c0 + 16 * w + nl;
    #pragma unroll
    for (int mt = 0; mt < 4; ++mt)
        #pragma unroll
        for (int r = 0; r < 4; ++r)
            atomicAdd(&ob[(size_t)(mt * 16 + q * 4 + r) * C_ + c], acc[mt][r]);
}

// ---------------------------------------------------------------------------
// Norm (fuses k_rnorm + k_final): one block per b. Wave w owns k = w+4i;
// per-k inv-norms stay in wave registers between the two passes; only the
// global norm crosses waves (one barrier). Math identical to the old pair.
// ---------------------------------------------------------------------------
__global__ __launch_bounds__(256) void k_norm(
    float* __restrict__ out, const float* __restrict__ centroids,
    const float* __restrict__ mass)
{
    const int b = blockIdx.x;
    const int t = threadIdx.x, lane = t & 63, w = t >> 6;
    __shared__ float gw[4];

    float* ob = out + (size_t)b * K_ * C_;
    float rn_r[16];
    float gacc = 0.f;

    #pragma unroll
    for (int i = 0; i < 16; ++i) {
        const int k = w + 4 * i;
        const float mk = mass[b * K_ + k];
        const float4 c0 = *(const float4*)(centroids + k * C_ + lane * 8);
        const float4 c1 = *(const float4*)(centroids + k * C_ + lane * 8 + 4);
        const float4 p0 = *(const float4*)(ob + k * C_ + lane * 8);
        const float4 p1 = *(const float4*)(ob + k * C_ + lane * 8 + 4);
        float vv, s;
        vv = fmaf(-c0.x, mk, p0.x); s  = vv * vv;
        vv = fmaf(-c0.y, mk, p0.y); s += vv * vv;
        vv = fmaf(-c0.z, mk, p0.z); s += vv * vv;
        vv = fmaf(-c0.w, mk, p0.w); s += vv * vv;
        vv = fmaf(-c1.x, mk, p1.x); s += vv * vv;
        vv = fmaf(-c1.y, mk, p1.y); s += vv * vv;
        vv = fmaf(-c1.z, mk, p1.z); s += vv * vv;
        vv = fmaf(-c1.w, mk, p1.w); s += vv * vv;
        #pragma unroll
        for (int o = 32; o > 0; o >>= 1) s += __shfl_down(s, o, 64);
        s = __shfl(s, 0, 64);                 // broadcast row sumsq
        const float rn = fmaxf(sqrtf(s), EPSF);
        rn_r[i] = rn;
        gacc += s / (rn * rn);
    }
    if (lane == 0) gw[w] = gacc;
    __syncthreads();
    const float gn = fmaxf(sqrtf(gw[0] + gw[1] + gw[2] + gw[3]), EPSF);

    #pragma unroll
    for (int i = 0; i < 16; ++i) {
        const int k = w + 4 * i;
        const float mk = mass[b * K_ + k];
        const float sc = 1.0f / (rn_r[i] * gn);
        const float4 c0 = *(const float4*)(centroids + k * C_ + lane * 8);
        const float4 c1 = *(const float4*)(centroids + k * C_ + lane * 8 + 4);
        float4 p0 = *(const float4*)(ob + k * C_ + lane * 8);
        float4 p1 = *(const float4*)(ob + k * C_ + lane * 8 + 4);
        p0.x = fmaf(-c0.x, mk, p0.x) * sc;
        p0.y = fmaf(-c0.y, mk, p0.y) * sc;
        p0.z = fmaf(-c0.z, mk, p0.z) * sc;
        p0.w = fmaf(-c0.w, mk, p0.w) * sc;
        p1.x = fmaf(-c1.x, mk, p1.x) * sc;
        p1.y = fmaf(-c1.y, mk, p1.y) * sc;
        p1.z = fmaf(-c1.z, mk, p1.z) * sc;
        p1.w = fmaf(-c1.w, mk, p1.w) * sc;
        *(float4*)(ob + k * C_ + lane * 8)     = p0;
        *(float4*)(ob + k * C_ + lane * 8 + 4) = p1;
    }
}

// ---------------------------------------------------------------------------
extern "C" void kernel_launch(void* const* d_in, const int* in_sizes, int n_in,
                              void* d_out, int out_size, void* d_ws, size_t ws_size,
                              hipStream_t stream) {
    const float* x         = (const float*)d_in[0];
    const float* centroids = (const float*)d_in[1];
    const float* conv_w    = (const float*)d_in[2];
    const float* conv_b    = (const float*)d_in[3];
    // d_in[4..8] (ghost_weights, w1, b1, w2, b2): positive per-row scalars
    // cancel inside the intra-cluster L2 norm; ghost rows dropped -> unused.

    float* out = (float*)d_out;
    char*  ws  = (char*)d_ws;

    u16*   assignp = (u16*)ws;                               // 16,777,216 B
    u16*   Wp      = (u16*)(ws + 16777216);                  // 81,920 B
    float* bpad    = (float*)(ws + 16777216 + 81920);        // 320 B
    float* mass    = (float*)(ws + 16777216 + 81920 + 320);  // 8 KB
    u16*   xbf     = (u16*)(ws + 33554432);                  // 134,217,728 B

    // 4 dispatches total (was 8): zeroing folded into k_prep, norm fused.
    k_prep<<<dim3(((B_ * K_ * C_) / 4 + B_ * K_ + 255) / 256), 256, 0, stream>>>(
        conv_w, conv_b, Wp, bpad, out, mass);
    k_assign<<<dim3(N_ / ANW, B_), 256, 0, stream>>>(x, Wp, bpad, assignp, xbf, mass);
    k_agg<<<dim3(C_ / 64, N_ / AGW, B_), 256, 0, stream>>>(xbf, assignp, out);
    k_norm<<<dim3(B_), 256, 0, stream>>>(out, centroids, mass);
}

// Round 8
// 516.115 us; speedup vs baseline: 1.4437x; 1.0860x over previous
//
#include <hip/hip_runtime.h>
#include <hip/hip_bf16.h>

#define B_ 32
#define C_ 512
#define N_ 4096
#define T_ 72
#define K_ 64
#define KP 80            // clusters padded to 5 MFMA m-tiles
#define EPSF 1e-12f

typedef unsigned short u16;
typedef unsigned int u32;
typedef __attribute__((ext_vector_type(8))) short bf16x8;
typedef __attribute__((ext_vector_type(4))) float f32x4;

__device__ __forceinline__ u16 f2bf(float v) {
    __hip_bfloat16 h = __float2bfloat16(v);   // RNE
    return *reinterpret_cast<u16*>(&h);
}

// ---------------------------------------------------------------------------
// Prep + zero-init (replaces 3 hipMemsetAsync dispatches): zero out + mass;
// W padded [80][512] -> bf16; bias padded (-1e30). grid 1032 x 256.
// ---------------------------------------------------------------------------
__global__ __launch_bounds__(256) void k_prep(
    const float* __restrict__ conv_w, const float* __restrict__ conv_b,
    u16* __restrict__ Wp, float* __restrict__ bp,
    float* __restrict__ out, float* __restrict__ mass)
{
    const int idx = blockIdx.x * 256 + threadIdx.x;
    if (idx < (B_ * K_ * C_) / 4)
        ((float4*)out)[idx] = make_float4(0.f, 0.f, 0.f, 0.f);
    else if (idx < (B_ * K_ * C_) / 4 + B_ * K_)
        mass[idx - (B_ * K_ * C_) / 4] = 0.f;

    if (idx < KP * C_) {
        const int k = idx >> 9, c = idx & (C_ - 1);
        Wp[idx] = f2bf(k < T_ ? conv_w[k * C_ + c] : 0.f);
    } else if (idx < KP * C_ + KP) {
        const int j = idx - KP * C_;
        bp[j] = (j < T_) ? conv_b[j] : -1e30f;
    }
}

// ---------------------------------------------------------------------------
// Assign v5: v3 + DEPTH-2 register double-buffer (va/vb). v3's prefetch-1
// gave loads only the MFMA phase (~400 cyc) to cover ~900-cyc HBM latency ->
// ~35% load duty cycle -> 2.0 TB/s. Depth-2 issues chunk ch+2's loads during
// MFMA(ch): window ~1.5 chunks > latency. Parity unrolled (compile-time reg
// indexing, rule #20). No xbf stores (round-7 vmcnt-FIFO mistake reverted).
// ---------------------------------------------------------------------------
#define ANW 256
__global__ __launch_bounds__(256, 2) void k_assign(
    const float* __restrict__ x, const u16* __restrict__ Wp,
    const float* __restrict__ bp, u16* __restrict__ assignp,
    float* __restrict__ mass)
{
    __shared__ u16   xs[ANW * 32];   // [n 256][c-chunk 32] bf16, 16 KB
    __shared__ float red[4][ANW];    // per-wave sumsq partials
    __shared__ float inv_sh[ANW];

    const int t = threadIdx.x;
    const int b = blockIdx.y;
    const int n0 = blockIdx.x * ANW;
    const int lane = t & 63, w = t >> 6;
    const int q = lane >> 4, nl = lane & 15;

    const float* xb = x + (size_t)b * C_ * N_ + n0 + 4 * lane;

    f32x4 acc[4][5];
    #pragma unroll
    for (int nt = 0; nt < 4; ++nt)
        #pragma unroll
        for (int mt = 0; mt < 5; ++mt) acc[nt][mt] = (f32x4)0.f;
    float ss[4] = {0.f, 0.f, 0.f, 0.f};

    float4 va[8], vb[8];
    bf16x8 af[5];
    // prologue: chunks 0 and 1 in flight (wave w owns c-rows w*8..w*8+8)
    #pragma unroll
    for (int i = 0; i < 8; ++i)
        va[i] = *(const float4*)(xb + (size_t)(w * 8 + i) * N_);
    #pragma unroll
    for (int i = 0; i < 8; ++i)
        vb[i] = *(const float4*)(xb + (size_t)(32 + w * 8 + i) * N_);
    #pragma unroll
    for (int mt = 0; mt < 5; ++mt)
        af[mt] = *(const bf16x8*)(Wp + (size_t)(mt * 16 + nl) * C_ + q * 8);

// consume buffer VB (8 float4 = 8c x 4n block) -> sumsq + c-contig LDS write
#define CONSUME(VB)                                                          \
    {                                                                        \
        _Pragma("unroll")                                                    \
        for (int j = 0; j < 4; ++j) {                                        \
            const float f0 = j==0?VB[0].x:j==1?VB[0].y:j==2?VB[0].z:VB[0].w; \
            const float f1 = j==0?VB[1].x:j==1?VB[1].y:j==2?VB[1].z:VB[1].w; \
            const float f2 = j==0?VB[2].x:j==1?VB[2].y:j==2?VB[2].z:VB[2].w; \
            const float f3 = j==0?VB[3].x:j==1?VB[3].y:j==2?VB[3].z:VB[3].w; \
            const float f4 = j==0?VB[4].x:j==1?VB[4].y:j==2?VB[4].z:VB[4].w; \
            const float f5 = j==0?VB[5].x:j==1?VB[5].y:j==2?VB[5].z:VB[5].w; \
            const float f6 = j==0?VB[6].x:j==1?VB[6].y:j==2?VB[6].z:VB[6].w; \
            const float f7 = j==0?VB[7].x:j==1?VB[7].y:j==2?VB[7].z:VB[7].w; \
            ss[j] = fmaf(f0, f0, ss[j]); ss[j] = fmaf(f1, f1, ss[j]);        \
            ss[j] = fmaf(f2, f2, ss[j]); ss[j] = fmaf(f3, f3, ss[j]);        \
            ss[j] = fmaf(f4, f4, ss[j]); ss[j] = fmaf(f5, f5, ss[j]);        \
            ss[j] = fmaf(f6, f6, ss[j]); ss[j] = fmaf(f7, f7, ss[j]);        \
            uint4 pk;                                                        \
            pk.x = (u32)f2bf(f0) | ((u32)f2bf(f1) << 16);                    \
            pk.y = (u32)f2bf(f2) | ((u32)f2bf(f3) << 16);                    \
            pk.z = (u32)f2bf(f4) | ((u32)f2bf(f5) << 16);                    \
            pk.w = (u32)f2bf(f6) | ((u32)f2bf(f7) << 16);                    \
            const int n = 4 * lane + j;                                      \
            const int slot = (w + ((lane >> 1) & 3)) & 3;                    \
            *(uint4*)&xs[n * 32 + slot * 8] = pk;                            \
        }                                                                    \
    }

// MFMA over current chunk's LDS tile
#define MFMA_PHASE()                                                         \
    {                                                                        \
        _Pragma("unroll")                                                    \
        for (int nt = 0; nt < 4; ++nt) {                                     \
            const int n = (4 * w + nt) * 16 + nl;                            \
            const int slot = (q + ((n >> 3) & 3)) & 3;                       \
            const bf16x8 bfr = *(const bf16x8*)&xs[n * 32 + slot * 8];       \
            _Pragma("unroll")                                                \
            for (int mt = 0; mt < 5; ++mt)                                   \
                acc[nt][mt] = __builtin_amdgcn_mfma_f32_16x16x32_bf16(       \
                    af[mt], bfr, acc[nt][mt], 0, 0, 0);                      \
        }                                                                    \
    }

    #pragma unroll 1
    for (int chp = 0; chp < 8; ++chp) {
        const int che = 2 * chp;          // even chunk (va), odd = che+1 (vb)
        // ---- even chunk ----
        CONSUME(va);
        __syncthreads();
        if (chp < 7) {
            #pragma unroll
            for (int i = 0; i < 8; ++i)
                va[i] = *(const float4*)(xb + (size_t)((che + 2) * 32 + w * 8 + i) * N_);
        }
        __builtin_amdgcn_sched_barrier(0);
        MFMA_PHASE();
        #pragma unroll
        for (int mt = 0; mt < 5; ++mt)    // W for odd chunk (L2-hot)
            af[mt] = *(const bf16x8*)(Wp + (size_t)(mt * 16 + nl) * C_ + (che + 1) * 32 + q * 8);
        __syncthreads();
        // ---- odd chunk ----
        CONSUME(vb);
        __syncthreads();
        if (chp < 7) {
            #pragma unroll
            for (int i = 0; i < 8; ++i)
                vb[i] = *(const float4*)(xb + (size_t)((che + 3) * 32 + w * 8 + i) * N_);
        }
        __builtin_amdgcn_sched_barrier(0);
        MFMA_PHASE();
        if (chp < 7) {
            #pragma unroll
            for (int mt = 0; mt < 5; ++mt)
                af[mt] = *(const bf16x8*)(Wp + (size_t)(mt * 16 + nl) * C_ + (che + 2) * 32 + q * 8);
        }
        __syncthreads();
    }
#undef CONSUME
#undef MFMA_PHASE

    // ---- cross-wave sumsq reduction -> inv norms ----
    *(float4*)&red[w][4 * lane] = make_float4(ss[0], ss[1], ss[2], ss[3]);
    __syncthreads();
    {
        const float s = red[0][t] + red[1][t] + red[2][t] + red[3][t];
        inv_sh[t] = 1.0f / fmaxf(sqrtf(s), EPSF);
    }
    __syncthreads();

    float bpv[5][4];
    #pragma unroll
    for (int mt = 0; mt < 5; ++mt)
        #pragma unroll
        for (int r = 0; r < 4; ++r) bpv[mt][r] = bp[mt * 16 + q * 4 + r];

    // ---- epilogue per n-tile: softmax in C-layout regs (proven math) ----
    #pragma unroll
    for (int nt = 0; nt < 4; ++nt) {
        const int n_loc = (4 * w + nt) * 16 + nl;
        const float invn = inv_sh[n_loc];
        const int nglob = n0 + n_loc;

        float lg[5][4];
        #pragma unroll
        for (int mt = 0; mt < 5; ++mt)
            #pragma unroll
            for (int r = 0; r < 4; ++r)
                lg[mt][r] = acc[nt][mt][r] * invn + bpv[mt][r];

        float mx = -1e30f;
        #pragma unroll
        for (int mt = 0; mt < 5; ++mt)
            #pragma unroll
            for (int r = 0; r < 4; ++r) mx = fmaxf(mx, lg[mt][r]);
        mx = fmaxf(mx, __shfl_xor(mx, 16, 64));
        mx = fmaxf(mx, __shfl_xor(mx, 32, 64));

        float s = 0.f;
        #pragma unroll
        for (int mt = 0; mt < 5; ++mt)
            #pragma unroll
            for (int r = 0; r < 4; ++r) {
                lg[mt][r] = __expf(lg[mt][r] - mx);
                s += lg[mt][r];
            }
        s += __shfl_xor(s, 16, 64);
        s += __shfl_xor(s, 32, 64);
        const float rs = 1.0f / s;

        #pragma unroll
        for (int mt = 0; mt < 4; ++mt)      // real clusters only
            #pragma unroll
            for (int r = 0; r < 4; ++r) {
                const float a = lg[mt][r] * rs;
                float msum = a;
                msum += __shfl_xor(msum, 1, 64);
                msum += __shfl_xor(msum, 2, 64);
                msum += __shfl_xor(msum, 4, 64);
                msum += __shfl_xor(msum, 8, 64);
                const int k = mt * 16 + q * 4 + r;
                if (nl == 0) atomicAdd(&mass[b * K_ + k], msum);
                assignp[((size_t)b * K_ + k) * N_ + nglob] = f2bf(a * invn);
            }
    }
}

// ---------------------------------------------------------------------------
// Agg v5 (EXACT round-5 version, probe-measured 76-81 us): all-LDS MFMA,
// prefetch-1, 34.8 KB LDS, fp32 x read.
// ---------------------------------------------------------------------------
#define AGW 1024
#define AGS 128
#define AGP 136
__global__ __launch_bounds__(256) void k_agg(
    const float* __restrict__ x, const u16* __restrict__ assignp,
    float* __restrict__ out)
{
    __shared__ u16 At[K_][AGP];   // 64 k x 128 n bf16, 17,408 B
    __shared__ u16 Bt[K_][AGP];   // 64 c x 128 n bf16, 17,408 B

    const int t = threadIdx.x, b = blockIdx.z;
    const int nc0 = blockIdx.y * AGW;
    const int c0 = blockIdx.x * 64;
    const int lane = t & 63, w = t >> 6;
    const int q = lane >> 4, nl = lane & 15;

    const int as = lane & 15, ar = lane >> 4;   // A: 16-B n-slot, row-in-4
    const int bs = lane & 31, br = lane >> 5;   // B: float4 n-slot, row-in-2

    f32x4 acc[4];
    #pragma unroll
    for (int mt = 0; mt < 4; ++mt) acc[mt] = (f32x4)0.f;

    const u16*   ab = assignp + (size_t)b * K_ * N_;
    const float* xb = x + ((size_t)b * C_ + c0) * N_;

    uint4  ra[4];
    float4 rb[8];
    #pragma unroll
    for (int i = 0; i < 4; ++i)
        ra[i] = *(const uint4*)(ab + (size_t)(16 * w + 4 * i + ar) * N_ + nc0 + as * 8);
    #pragma unroll
    for (int i = 0; i < 8; ++i)
        rb[i] = *(const float4*)(xb + (size_t)(16 * w + 2 * i + br) * N_ + nc0 + bs * 4);

    #pragma unroll 1
    for (int ph = 0; ph < AGW / AGS; ++ph) {
        #pragma unroll
        for (int i = 0; i < 4; ++i)
            *(uint4*)&At[16 * w + 4 * i + ar][as * 8] = ra[i];
        #pragma unroll
        for (int i = 0; i < 8; ++i) {
            const float4 vv = rb[i];
            uint2 pk;
            pk.x = (u32)f2bf(vv.x) | ((u32)f2bf(vv.y) << 16);
            pk.y = (u32)f2bf(vv.z) | ((u32)f2bf(vv.w) << 16);
            *(uint2*)&Bt[16 * w + 2 * i + br][bs * 4] = pk;
        }
        __syncthreads();
        if (ph < AGW / AGS - 1) {
            const int n1 = nc0 + (ph + 1) * AGS;
            #pragma unroll
            for (int i = 0; i < 4; ++i)
                ra[i] = *(const uint4*)(ab + (size_t)(16 * w + 4 * i + ar) * N_ + n1 + as * 8);
            #pragma unroll
            for (int i = 0; i < 8; ++i)
                rb[i] = *(const float4*)(xb + (size_t)(16 * w + 2 * i + br) * N_ + n1 + bs * 4);
        }
        __builtin_amdgcn_sched_barrier(0);
        #pragma unroll
        for (int ks = 0; ks < 4; ++ks) {
            const bf16x8 bfr = *(const bf16x8*)&Bt[16 * w + nl][ks * 32 + q * 8];
            #pragma unroll
            for (int mt = 0; mt < 4; ++mt) {
                const bf16x8 afv = *(const bf16x8*)&At[mt * 16 + nl][ks * 32 + q * 8];
                acc[mt] = __builtin_amdgcn_mfma_f32_16x16x32_bf16(afv, bfr, acc[mt], 0, 0, 0);
            }
        }
        __syncthreads();
    }

    float* ob = out + (size_t)b * K_ * C_;
    const int c = c0 + 16 * w + nl;
    #pragma unroll
    for (int mt = 0; mt < 4; ++mt)
        #pragma unroll
        for (int r = 0; r < 4; ++r)
            atomicAdd(&ob[(size_t)(mt * 16 + q * 4 + r) * C_ + c], acc[mt][r]);
}

// ---------------------------------------------------------------------------
// Row norms + global norm (fp32 exact), round-5 versions (large grids).
// ---------------------------------------------------------------------------
__device__ __forceinline__ float block_reduce_sum_256(float v) {
    #pragma unroll
    for (int o = 32; o > 0; o >>= 1) v += __shfl_down(v, o, 64);
    __shared__ float wsh[4];
    const int lane = threadIdx.x & 63, wid = threadIdx.x >> 6;
    if (lane == 0) wsh[wid] = v;
    __syncthreads();
    float r = 0.f;
    if (threadIdx.x == 0) r = wsh[0] + wsh[1] + wsh[2] + wsh[3];
    return r;
}

__global__ __launch_bounds__(256) void k_rnorm(
    const float* __restrict__ agg, const float* __restrict__ centroids,
    const float* __restrict__ mass, float* __restrict__ rnorm,
    float* __restrict__ gsum)
{
    const int k = blockIdx.x, b = blockIdx.y;
    const float mk = mass[b * K_ + k];
    const float* p  = agg + ((size_t)b * K_ + k) * C_;
    const float* cb = centroids + k * C_;
    float s = 0.f;
    #pragma unroll 2
    for (int i = threadIdx.x; i < C_; i += 256) {
        const float v = fmaf(-cb[i], mk, p[i]);
        s = fmaf(v, v, s);
    }
    const float ss = block_reduce_sum_256(s);
    if (threadIdx.x == 0) {
        const float rn = fmaxf(sqrtf(ss), EPSF);
        rnorm[b * K_ + k] = rn;
        atomicAdd(gsum + b, ss / (rn * rn));
    }
}

__global__ __launch_bounds__(256) void k_final(
    float* __restrict__ out, const float* __restrict__ centroids,
    const float* __restrict__ mass, const float* __restrict__ rnorm,
    const float* __restrict__ gsum)
{
    const size_t i4 = ((size_t)blockIdx.x * 256 + threadIdx.x) * 4;
    const int b = (int)(i4 >> 15);
    const int k = (int)((i4 >> 9) & 63);
    const int c = (int)(i4 & 511);
    const float gn = fmaxf(sqrtf(gsum[b]), EPSF);
    const float sc = 1.0f / (rnorm[b * K_ + k] * gn);
    const float mk = mass[b * K_ + k];
    float4 v  = *(const float4*)(out + i4);
    const float4 cv = *(const float4*)(centroids + k * C_ + c);
    v.x = fmaf(-cv.x, mk, v.x) * sc;
    v.y = fmaf(-cv.y, mk, v.y) * sc;
    v.z = fmaf(-cv.z, mk, v.z) * sc;
    v.w = fmaf(-cv.w, mk, v.w) * sc;
    *(float4*)(out + i4) = v;
}

// ---------------------------------------------------------------------------
extern "C" void kernel_launch(void* const* d_in, const int* in_sizes, int n_in,
                              void* d_out, int out_size, void* d_ws, size_t ws_size,
                              hipStream_t stream) {
    const float* x         = (const float*)d_in[0];
    const float* centroids = (const float*)d_in[1];
    const float* conv_w    = (const float*)d_in[2];
    const float* conv_b    = (const float*)d_in[3];
    // d_in[4..8] (ghost_weights, w1, b1, w2, b2): positive per-row scalars
    // cancel inside the intra-cluster L2 norm; ghost rows dropped -> unused.

    float* out = (float*)d_out;
    char*  ws  = (char*)d_ws;

    u16*   assignp = (u16*)ws;                               // 16,777,216 B
    u16*   Wp      = (u16*)(ws + 16777216);                  // 81,920 B
    float* bpad    = (float*)(ws + 16777216 + 81920);        // 320 B
    float* mass    = (float*)(ws + 16777216 + 81920 + 320);  // 8 KB
    float* rnorm   = mass + B_ * K_;
    float* gsum    = rnorm + B_ * K_;

    // gsum needs zeroing (atomicAdd target); fold into prep? it is tiny ->
    // zero via k_prep's mass path would change layout; keep one memset.
    hipMemsetAsync(gsum, 0, B_ * sizeof(float), stream);

    k_prep<<<dim3(((B_ * K_ * C_) / 4 + B_ * K_ + 255) / 256), 256, 0, stream>>>(
        conv_w, conv_b, Wp, bpad, out, mass);
    k_assign<<<dim3(N_ / ANW, B_), 256, 0, stream>>>(x, Wp, bpad, assignp, mass);
    k_agg<<<dim3(C_ / 64, N_ / AGW, B_), 256, 0, stream>>>(x, assignp, out);
    k_rnorm<<<dim3(K_, B_), 256, 0, stream>>>(out, centroids, mass, rnorm, gsum);
    k_final<<<(out_size / 4 + 255) / 256, 256, 0, stream>>>(out, centroids, mass, rnorm, gsum);
}